// Round 7
// baseline (6855.074 us; speedup 1.0000x reference)
//
#include <hip/hip_runtime.h>

#define TSTEPS 512
#define BATCH  256
#define HID    256
#define OUTC   256

typedef _Float16 half8 __attribute__((ext_vector_type(8)));
typedef float    f32x4 __attribute__((ext_vector_type(4)));
union G16 { unsigned long long u2[2]; unsigned u[4]; half8 h; };

// h0 ring: [32 slots][16 grp][16 row][128 pair] u64 (tag|2xf16)   8 MB
// h1 ring: [ 4 slots][16 grp][2 hs][16 row][64 pair] u64          1 MB
#define H0_SLOTS 32
#define H0RING_QW (H0_SLOTS*16*16*128)
#define H1RING_QW (4*16*2*16*64)

__device__ __forceinline__ float sigf(float x){ return 1.0f/(1.0f+__expf(-x)); }
__device__ __forceinline__ float tanh_(float x){
  float a = fminf(fmaxf(x,-8.0f),8.0f);
  float e = __expf(2.0f*a);
  return (e-1.0f)/(e+1.0f);
}
__device__ __forceinline__ void st64(unsigned long long* p, unsigned long long v){
  __hip_atomic_store(p, v, __ATOMIC_RELAXED, __HIP_MEMORY_SCOPE_AGENT);
}
__device__ __forceinline__ unsigned long long ld64(const unsigned long long* p){
  return __hip_atomic_load(p, __ATOMIC_RELAXED, __HIP_MEMORY_SCOPE_AGENT);
}
__device__ __forceinline__ void st32(unsigned* p, unsigned v){
  __hip_atomic_store(p, v, __ATOMIC_RELAXED, __HIP_MEMORY_SCOPE_AGENT);
}
__device__ __forceinline__ unsigned ld32(const unsigned* p){
  return __hip_atomic_load(p, __ATOMIC_RELAXED, __HIP_MEMORY_SCOPE_AGENT);
}

// ---------------- prep kernels ----------------
__global__ void prep_convert(const float* __restrict__ Wih, const float* __restrict__ Whh,
                             const float* __restrict__ fcw, const float* __restrict__ bih,
                             const float* __restrict__ bhh,
                             _Float16* __restrict__ wh0, _Float16* __restrict__ wi1,
                             _Float16* __restrict__ wh1, _Float16* __restrict__ fcwh,
                             float* __restrict__ bias1)
{
  int i = blockIdx.x*256 + threadIdx.x;
  wh0[i] = (_Float16)Whh[i];
  wi1[i] = (_Float16)Wih[262144 + i];
  wh1[i] = (_Float16)Whh[262144 + i];
  if (i < 65536) fcwh[i] = (_Float16)fcw[i];
  if (i < 1024)  bias1[i] = bih[1024+i] + bhh[1024+i];
}

__global__ void prep_gx0(const float* __restrict__ x, const float* __restrict__ Wih,
                         const float* __restrict__ bih, const float* __restrict__ bhh,
                         float* __restrict__ gx0)
{
  int gid = blockIdx.x*256 + threadIdx.x;
  int b = gid >> 10, n = gid & 1023;
  const float4* xv = (const float4*)(x + (size_t)b*256);
  const float4* wv = (const float4*)(Wih + (size_t)n*256);
  float s = bih[n] + bhh[n];
  #pragma unroll 8
  for (int k=0;k<64;k++){
    float4 a = xv[k], c = wv[k];
    s += a.x*c.x + a.y*c.y + a.z*c.z + a.w*c.w;
  }
  gx0[gid] = s;
}

__global__ void zero_scratch(unsigned long long* __restrict__ base, int total){
  int i = blockIdx.x*256 + threadIdx.x;
  if (i < total) st64(base + i, 0ull);
}

// ================= fused LSTM, VGPR-resident weights: 48 WGs x 512 thr ========
// blk 0-15:  layer0, self-contained per 16-row group. Wh0 512KB in VGPRs
//            (256/lane). h0 recurrence entirely in LDS. Ring publish f&f.
// blk 16-47: layer1, 2-way j-split (hs = half of 256 cols). 512KB weights in
//            VGPRs. partA (Wi1*h0) overlaps the peer-half h1 flight.
__global__ __launch_bounds__(512,1) void lstm5(
    const float* __restrict__ gx0, const _Float16* __restrict__ Wh0g,
    const _Float16* __restrict__ Wi1g, const _Float16* __restrict__ Wh1g,
    const float* __restrict__ bias1, const float* __restrict__ h_in,
    const float* __restrict__ c_in, unsigned* __restrict__ seq1dw,
    unsigned long long* __restrict__ h0r, unsigned long long* __restrict__ h1r,
    unsigned* __restrict__ flagC)
{
  __shared__ __align__(16) _Float16 shA[8192];   // 16 KB: h0 tile double-buf
  __shared__ __align__(16) _Float16 shB[8192];   // 16 KB: h1 tile double-buf (l1)

  const int blk = blockIdx.x, tid = threadIdx.x;
  const int w = tid>>6, l = tid&63, c16 = l&15, kg = l>>4;

  if (blk < 16){
    // ================= layer 0: self-contained =================
    const int grp = blk, b0 = grp*16;
    half8 wreg[2][4][8];                 // 256 VGPRs: cols w*32+p*16+c16, 4 gates
    #pragma unroll
    for (int p=0;p<2;p++)
      #pragma unroll
      for (int g=0;g<4;g++){
        const _Float16* src = Wh0g + ((size_t)(g*256 + w*32 + p*16 + c16))*256 + kg*8;
        #pragma unroll
        for (int kt=0;kt<8;kt++) wreg[p][g][kt] = *(const half8*)(src + kt*32);
      }
    { int row = tid>>5, q = tid&31;      // init h0(-1) -> buf 0
      const float* sp = h_in + (size_t)(b0+row)*256 + q*8;
      half8 v;
      #pragma unroll
      for (int qq=0;qq<8;qq++) v[qq] = (_Float16)sp[qq];
      *(half8*)&shA[row*256 + (q^(row&7))*8] = v; }
    f32x4 gxr[2][4];
    float cs[2][4];
    #pragma unroll
    for (int p=0;p<2;p++){
      #pragma unroll
      for (int g=0;g<4;g++)
        #pragma unroll
        for (int r=0;r<4;r++)
          gxr[p][g][r] = gx0[(size_t)(b0+kg*4+r)*1024 + g*256 + w*32 + p*16 + c16];
      #pragma unroll
      for (int r=0;r<4;r++)
        cs[p][r] = c_in[(size_t)(b0+kg*4+r)*256 + w*32 + p*16 + c16];
    }
    __syncthreads();

    for (int t=0; t<TSTEPS; ++t){
      if (((t&7)==0) && t>=32 && tid==0){   // ring-overwrite throttle (rare)
        while (ld32(&flagC[grp]) + 24u < (unsigned)t) __builtin_amdgcn_s_sleep(8);
      }
      __syncthreads();                      // cell writes (t-1) visible
      const _Float16* sc = &shA[(t&1)*4096];
      half8 af[8];
      #pragma unroll
      for (int kt=0;kt<8;kt++)
        af[kt] = *(const half8*)&sc[c16*256 + (((kt*4+kg)^(c16&7)))*8];
      f32x4 acc[2][4];
      #pragma unroll
      for (int p=0;p<2;p++)
        #pragma unroll
        for (int g=0;g<4;g++) acc[p][g] = gxr[p][g];
      #pragma unroll
      for (int kt=0;kt<8;kt++)
        #pragma unroll
        for (int p=0;p<2;p++)
          #pragma unroll
          for (int g=0;g<4;g++)
            acc[p][g] = __builtin_amdgcn_mfma_f32_16x16x32_f16(af[kt], wreg[p][g][kt], acc[p][g], 0,0,0);
      char* shn = (char*)&shA[((t+1)&1)*4096];
      unsigned long long tg = ((unsigned long long)(unsigned)(t+2))<<32;
      unsigned long long* ring = h0r + ((size_t)(t&(H0_SLOTS-1))*16 + grp)*2048;
      #pragma unroll
      for (int p=0;p<2;p++){
        int jg = w*32 + p*16 + c16;
        #pragma unroll
        for (int r=0;r<4;r++){
          float iv=sigf(acc[p][0][r]), fv=sigf(acc[p][1][r]);
          float gv=tanh_(acc[p][2][r]), ov=sigf(acc[p][3][r]);
          float cn = fv*cs[p][r] + iv*gv; cs[p][r] = cn;
          float hn = ov*tanh_(cn);
          unsigned u16 = (unsigned)__builtin_bit_cast(unsigned short,(_Float16)hn);
          unsigned up  = (unsigned)__shfl_xor((int)u16, 1, 64);
          if (!(c16&1)){
            unsigned pk = u16 | (up<<16);
            int row = kg*4+r;
            *(unsigned*)(shn + row*512 + ((jg>>3)^(row&7))*16 + (jg&7)*2) = pk;
            st64(&ring[(size_t)row*128 + (jg>>1)], tg | pk);
          }
        }
      }
    }
  } else {
    // ================= layer 1: 2-way j-split =================
    const int bb = blk-16, grp = bb>>1, hs = bb&1, b0 = grp*16;
    const int mycol = hs*128 + w*16 + c16;
    half8 wregA[4][8], wregB[4][8];      // 256 VGPRs
    #pragma unroll
    for (int g=0;g<4;g++){
      const _Float16* sa = Wi1g + ((size_t)(g*256+mycol))*256 + kg*8;
      const _Float16* sb = Wh1g + ((size_t)(g*256+mycol))*256 + kg*8;
      #pragma unroll
      for (int kt=0;kt<8;kt++){
        wregA[g][kt] = *(const half8*)(sa + kt*32);
        wregB[g][kt] = *(const half8*)(sb + kt*32);
      }
    }
    float bv[4], cs[4];
    #pragma unroll
    for (int g=0;g<4;g++) bv[g] = bias1[g*256 + mycol];
    #pragma unroll
    for (int r=0;r<4;r++)
      cs[r] = c_in[65536 + (size_t)(b0+kg*4+r)*256 + mycol];
    { int row = tid>>5, q = tid&31;      // init h1(-1) -> shB buf 0 (full tile)
      const float* sp = h_in + 65536 + (size_t)(b0+row)*256 + q*8;
      half8 v;
      #pragma unroll
      for (int qq=0;qq<8;qq++) v[qq] = (_Float16)sp[qq];
      *(half8*)&shB[row*256 + (q^(row&7))*8] = v; }
    const int prow = tid>>5, ppc = (tid&31)*4;    // h0 prefetch mapping
    unsigned long long hv0,hv1,hv2,hv3;
    { const unsigned long long* hp = h0r + ((size_t)grp)*2048 + (size_t)prow*128 + ppc;
      hv0=ld64(hp); hv1=ld64(hp+1); hv2=ld64(hp+2); hv3=ld64(hp+3); }
    __syncthreads();

    for (int t=0; t<TSTEPS; ++t){
      { // verify prefetched h0(t); stage to shA[t&1]
        unsigned tg32 = (unsigned)(t+2);
        const unsigned long long* hp =
          h0r + ((size_t)(t&(H0_SLOTS-1))*16 + grp)*2048 + (size_t)prow*128 + ppc;
        while (!((unsigned)(hv0>>32)==tg32 && (unsigned)(hv1>>32)==tg32 &&
                 (unsigned)(hv2>>32)==tg32 && (unsigned)(hv3>>32)==tg32)){
          hv0=ld64(hp); hv1=ld64(hp+1); hv2=ld64(hp+2); hv3=ld64(hp+3);
        }
        G16 g16; g16.u[0]=(unsigned)hv0; g16.u[1]=(unsigned)hv1;
                 g16.u[2]=(unsigned)hv2; g16.u[3]=(unsigned)hv3;
        *(half8*)&shA[(t&1)*4096 + prow*256 + (((tid&31)^(prow&7)))*8] = g16.h;
      }
      if (hs==0 && tid==0 && (t&7)==0) st32(&flagC[grp], (unsigned)t);
      __syncthreads();
      // ---- partA: bias + Wi1 . h0(t) (overlaps peer h1 flight) ----
      const _Float16* sa = &shA[(t&1)*4096];
      half8 af[8];
      #pragma unroll
      for (int kt=0;kt<8;kt++)
        af[kt] = *(const half8*)&sa[c16*256 + (((kt*4+kg)^(c16&7)))*8];
      f32x4 acc[4];
      #pragma unroll
      for (int g=0;g<4;g++) acc[g] = (f32x4){bv[g],bv[g],bv[g],bv[g]};
      #pragma unroll
      for (int kt=0;kt<8;kt++)
        #pragma unroll
        for (int g=0;g<4;g++)
          acc[g] = __builtin_amdgcn_mfma_f32_16x16x32_f16(af[kt], wregA[g][kt], acc[g], 0,0,0);
      // ---- poll + stage peer half of h1(t-1) ----
      if (t > 0){
        unsigned tgp = (unsigned)(t+1);
        int row = tid>>5, pc = (tid&31)*2;
        const unsigned long long* pp =
          h1r + ((((size_t)((t-1)&3)*16+grp)*2 + (1-hs))*16 + row)*64 + pc;
        unsigned long long a,b;
        do { a = ld64(pp); b = ld64(pp+1); }
        while (!((unsigned)(a>>32)==tgp && (unsigned)(b>>32)==tgp));
        int c0 = (1-hs)*128 + pc*2;
        unsigned long long dat = (unsigned long long)(unsigned)a
                               | (((unsigned long long)(unsigned)b)<<32);
        *(unsigned long long*)((char*)&shB[(t&1)*4096]
            + row*512 + ((c0>>3)^(row&7))*16 + (c0&7)*2) = dat;
      }
      __syncthreads();
      // ---- partB: += Wh1 . h1(t-1) ----
      const _Float16* sb = &shB[(t&1)*4096];
      #pragma unroll
      for (int kt=0;kt<8;kt++)
        af[kt] = *(const half8*)&sb[c16*256 + (((kt*4+kg)^(c16&7)))*8];
      #pragma unroll
      for (int kt=0;kt<8;kt++)
        #pragma unroll
        for (int g=0;g<4;g++)
          acc[g] = __builtin_amdgcn_mfma_f32_16x16x32_f16(af[kt], wregB[g][kt], acc[g], 0,0,0);
      { // ---- cell + own-half write + publish + seq1 ----
        unsigned long long tg = ((unsigned long long)(unsigned)(t+2))<<32;
        char* shn = (char*)&shB[((t+1)&1)*4096];
        unsigned long long* ring = h1r + (((size_t)(t&3)*16+grp)*2 + hs)*1024;
        #pragma unroll
        for (int r=0;r<4;r++){
          float iv=sigf(acc[0][r]), fv=sigf(acc[1][r]);
          float gv=tanh_(acc[2][r]), ov=sigf(acc[3][r]);
          float cn = fv*cs[r] + iv*gv; cs[r] = cn;
          float hn = ov*tanh_(cn);
          unsigned u16 = (unsigned)__builtin_bit_cast(unsigned short,(_Float16)hn);
          unsigned up  = (unsigned)__shfl_xor((int)u16, 1, 64);
          if (!(c16&1)){
            unsigned pk = u16 | (up<<16);
            int row = kg*4+r;
            *(unsigned*)(shn + row*512 + ((mycol>>3)^(row&7))*16 + (mycol&7)*2) = pk;
            st64(&ring[(size_t)row*64 + ((mycol&127)>>1)], tg | pk);
            seq1dw[((size_t)(b0+row)*TSTEPS + t)*256 + (mycol>>1)] = pk;
          }
        }
      }
      if (t+1 < TSTEPS){  // prefetch h0(t+1)
        const unsigned long long* hp2 =
          h0r + ((size_t)((t+1)&(H0_SLOTS-1))*16 + grp)*2048 + (size_t)prow*128 + ppc;
        hv0=ld64(hp2); hv1=ld64(hp2+1); hv2=ld64(hp2+2); hv3=ld64(hp2+3);
      }
    }
  }
}

// ---------------- FC + log_softmax / softmax ----------------
__global__ __launch_bounds__(256) void fc_kernel(
    const _Float16* __restrict__ seq, int pitch,
    const _Float16* __restrict__ fcwh, const float* __restrict__ fcb,
    float* __restrict__ out0, float* __restrict__ out1)
{
  const int tid = threadIdx.x;
  const int w = tid >> 6, l = tid & 63;
  const int col = l & 15, kg = l >> 4;
  const size_t m0 = (size_t)blockIdx.x*64 + (size_t)w*16;
  half8 a[8];
  #pragma unroll
  for (int kt=0;kt<8;kt++)
    a[kt] = *(const half8*)&seq[(m0+col)*(size_t)pitch + kt*32 + kg*8];
  f32x4 acc[16];
  #pragma unroll
  for (int nt=0;nt<16;nt++){
    int n = nt*16 + col;
    float bvl = fcb[n];
    f32x4 c = {bvl,bvl,bvl,bvl};
    const _Float16* wr = fcwh + (size_t)n*256;
    #pragma unroll
    for (int kt=0;kt<8;kt++){
      half8 bf = *(const half8*)&wr[kt*32 + kg*8];
      c = __builtin_amdgcn_mfma_f32_16x16x32_f16(a[kt], bf, c, 0,0,0);
    }
    acc[nt] = c;
  }
  #pragma unroll
  for (int r=0;r<4;r++){
    float mx = -3.0e38f;
    #pragma unroll
    for (int nt=0;nt<16;nt++) mx = fmaxf(mx, acc[nt][r]);
    #pragma unroll
    for (int off=1; off<16; off<<=1) mx = fmaxf(mx, __shfl_xor(mx, off, 64));
    float s = 0.0f;
    #pragma unroll
    for (int nt=0;nt<16;nt++) s += __expf(acc[nt][r]-mx);
    #pragma unroll
    for (int off=1; off<16; off<<=1) s += __shfl_xor(s, off, 64);
    float inv = 1.0f/s;
    float ls  = __logf(s);
    size_t row = m0 + (size_t)kg*4 + r;
    #pragma unroll
    for (int nt=0;nt<16;nt++){
      int n = nt*16 + col;
      float v = acc[nt][r]-mx;
      out0[row*256 + n] = v - ls;
      out1[row*256 + n] = __expf(v)*inv;
    }
  }
}

extern "C" void kernel_launch(void* const* d_in, const int* in_sizes, int n_in,
                              void* d_out, int out_size, void* d_ws, size_t ws_size,
                              hipStream_t stream)
{
  const float* x   = (const float*)d_in[0];
  const float* h0  = (const float*)d_in[1];
  const float* c0  = (const float*)d_in[2];
  const float* Wih = (const float*)d_in[3];
  const float* Whh = (const float*)d_in[4];
  const float* bih = (const float*)d_in[5];
  const float* bhh = (const float*)d_in[6];
  const float* fcw = (const float*)d_in[7];
  const float* fcb = (const float*)d_in[8];
  (void)in_sizes; (void)n_in; (void)out_size; (void)ws_size;

  char* ws = (char*)d_ws;
  _Float16* wh0   = (_Float16*)(ws + 0);            // 512 KB
  _Float16* wi1   = (_Float16*)(ws + (512<<10));    // 512 KB
  _Float16* wh1   = (_Float16*)(ws + (1024<<10));   // 512 KB
  _Float16* fcwh  = (_Float16*)(ws + (1536<<10));   // 128 KB
  float*    bias1 = (float*)   (ws + (1664<<10));   // 4 KB
  float*    gx0   = (float*)   (ws + (1668<<10));   // 1 MB

  // d_out scratch (out0 region, fully overwritten by fc at the end):
  //   h0 ring 8 MB | h1 ring 1 MB | flagC 64 B
  char* ob = (char*)d_out;
  float* out0 = (float*)d_out;
  float* out1 = out0 + (size_t)BATCH*TSTEPS*OUTC;
  unsigned long long* h0r   = (unsigned long long*)ob;
  unsigned long long* h1r   = h0r + H0RING_QW;
  unsigned*           flagC = (unsigned*)(h1r + H1RING_QW);
  unsigned* seq1dw = (unsigned*)out1;               // seq1 overlay, pitch 512 f16
  _Float16* seq1   = (_Float16*)out1;

  const int zeroQW = H0RING_QW + H1RING_QW + 8;
  hipLaunchKernelGGL(zero_scratch, dim3((zeroQW+255)/256), dim3(256), 0, stream,
                     h0r, zeroQW);
  hipLaunchKernelGGL(prep_convert, dim3(1024), dim3(256), 0, stream,
                     Wih, Whh, fcw, bih, bhh, wh0, wi1, wh1, fcwh, bias1);
  hipLaunchKernelGGL(prep_gx0, dim3(1024), dim3(256), 0, stream,
                     x, Wih, bih, bhh, gx0);
  hipLaunchKernelGGL(lstm5, dim3(48), dim3(512), 0, stream,
                     gx0, wh0, wi1, wh1, bias1, h0, c0,
                     seq1dw, h0r, h1r, flagC);
  hipLaunchKernelGGL(fc_kernel, dim3(2048), dim3(256), 0, stream,
                     seq1, 512, fcwh, fcb, out0, out1);
}

// Round 9
// 1905.392 us; speedup vs baseline: 3.5977x; 3.5977x over previous
//
#include <hip/hip_runtime.h>

#define TSTEPS 512
#define BATCH  256
#define HID    256
#define OUTC   256

typedef _Float16 half8 __attribute__((ext_vector_type(8)));
typedef float    f32x4 __attribute__((ext_vector_type(4)));
typedef int      i32x4 __attribute__((ext_vector_type(4)));

// exchange buffers in d_out scratch (tag-free data + separate flags):
// h0 ring: [16 slots][16 grp][16 row][256 col] f16   (2 MB)
// h1 ring: [ 4 slots][16 grp][16 row][256 col] f16   (512 KB)
// h0flag:  [16 grp][16 slot][4 prod]  u32  == t+2 when h0(t) complete
// h1flag:  [16 grp][ 4 slot][8 prod]  u32  == t+2 when h1(t) complete
// flagC :  [16 grp][8 js] monotonic ack (every 8 steps)
#define H0_SLOTS 16
#define H1_SLOTS 4
#define SPIN_CAP 65536

__device__ __forceinline__ float sigf(float x){ return 1.0f/(1.0f+__expf(-x)); }
__device__ __forceinline__ float tanh_(float x){
  float a = fminf(fmaxf(x,-8.0f),8.0f);
  float e = __expf(2.0f*a);
  return (e-1.0f)/(e+1.0f);
}
// flags: agent-scope atomics (tiny traffic)
__device__ __forceinline__ void st32a(unsigned* p, unsigned v){
  __hip_atomic_store(p, v, __ATOMIC_RELAXED, __HIP_MEMORY_SCOPE_AGENT);
}
__device__ __forceinline__ unsigned ld32a(const unsigned* p){
  return __hip_atomic_load(p, __ATOMIC_RELAXED, __HIP_MEMORY_SCOPE_AGENT);
}
// data: plain wide agent-visible (sc1) ops — coalesce into full MALL lines
__device__ __forceinline__ void st32_sc1(void* p, unsigned v){
  asm volatile("global_store_dword %0, %1, off sc1" :: "v"(p), "v"(v) : "memory");
}
__device__ __forceinline__ half8 ld128_sc1(const void* p){
  i32x4 r;
  asm volatile("global_load_dwordx4 %0, %1, off sc1\n\ts_waitcnt vmcnt(0)"
               : "=&v"(r) : "v"(p) : "memory");
  return __builtin_bit_cast(half8, r);
}
__device__ __forceinline__ unsigned pack2(float a, float b){
  _Float16 x=(_Float16)a, y=(_Float16)b;
  return (unsigned)__builtin_bit_cast(unsigned short,x)
       | ((unsigned)__builtin_bit_cast(unsigned short,y)<<16);
}

// ---------------- prep kernels ----------------
__global__ void prep_convert(const float* __restrict__ Wih, const float* __restrict__ Whh,
                             const float* __restrict__ fcw, const float* __restrict__ bih,
                             const float* __restrict__ bhh,
                             _Float16* __restrict__ wh0, _Float16* __restrict__ wi1,
                             _Float16* __restrict__ wh1, _Float16* __restrict__ fcwh,
                             float* __restrict__ bias1)
{
  int i = blockIdx.x*256 + threadIdx.x;
  wh0[i] = (_Float16)Whh[i];
  wi1[i] = (_Float16)Wih[262144 + i];
  wh1[i] = (_Float16)Whh[262144 + i];
  if (i < 65536) fcwh[i] = (_Float16)fcw[i];
  if (i < 1024)  bias1[i] = bih[1024+i] + bhh[1024+i];
}

__global__ void prep_gx0(const float* __restrict__ x, const float* __restrict__ Wih,
                         const float* __restrict__ bih, const float* __restrict__ bhh,
                         float* __restrict__ gx0)
{
  int gid = blockIdx.x*256 + threadIdx.x;
  int b = gid >> 10, n = gid & 1023;
  const float4* xv = (const float4*)(x + (size_t)b*256);
  const float4* wv = (const float4*)(Wih + (size_t)n*256);
  float s = bih[n] + bhh[n];
  #pragma unroll 8
  for (int k=0;k<64;k++){
    float4 a = xv[k], c = wv[k];
    s += a.x*c.x + a.y*c.y + a.z*c.z + a.w*c.w;
  }
  gx0[gid] = s;
}

__global__ void zero_flags(unsigned* __restrict__ f, int total){
  int i = blockIdx.x*256 + threadIdx.x;
  if (i < total) f[i] = 0u;
}

// ============ fused 2-layer LSTM: 192 WGs (R6 skeleton, coalesced exchange) ===
// blk<64:  layer0. 16 grps x 4 j-slices (64 cols). Wh0 slice 128 KB LDS.
// blk>=64: layer1. 16 grps x 8 j-slices (32 cols). [Wi1|Wh1] slice 128 KB LDS.
// Data tiles are tag-free f16, stored dword sc1, read dwordx4 sc1 (coalesced).
// Per-(grp,producer,slot) flag written after vmcnt(0)+barrier; bounded spins.
__global__ __launch_bounds__(512,1) void lstm7(
    const float* __restrict__ gx0, const _Float16* __restrict__ Wh0g,
    const _Float16* __restrict__ Wi1g, const _Float16* __restrict__ Wh1g,
    const float* __restrict__ bias1, const float* __restrict__ h_in,
    const float* __restrict__ c_in, unsigned* __restrict__ seq1dw,
    _Float16* __restrict__ h0r, _Float16* __restrict__ h1r,
    unsigned* __restrict__ h0flag, unsigned* __restrict__ h1flag,
    unsigned* __restrict__ flagC)
{
  __shared__ __align__(16) char Lb[156160];
  _Float16* Ws  = (_Float16*)Lb;              // 128 KB weights
  _Float16* sh0 = (_Float16*)(Lb + 131072);   // 8 KB h0 tile (swizzled)

  const int blk = blockIdx.x, tid = threadIdx.x;
  const int wv = tid>>6, l = tid&63, c16 = l&15, kg = l>>4;

  if (blk < 64){
    // ---------------- layer 0 ----------------
    const int grp = blk>>2, s = blk&3, b0 = grp*16;
    const int gate = wv>>1, jblk = (wv&1)*32;
    float (*gbuf)[16][66] = (float (*)[16][66])(Lb + 139264);  // 16.9 KB

    for (int idx=tid; idx<8192; idx+=512){
      int row = idx>>5, gr = idx&31;
      int g = row>>6, jl = row&63;
      half8 v = *(const half8*)(Wh0g + ((size_t)(g*256 + s*64 + jl))*256 + gr*8);
      *(half8*)&Ws[row*256 + (gr^(row&7))*8] = v;
    }
    { int row = tid>>5, q = tid&31;
      const float* sp = h_in + (size_t)(b0+row)*256 + q*8;
      half8 v;
      #pragma unroll
      for (int qq=0;qq<8;qq++) v[qq] = (_Float16)sp[qq];
      *(half8*)&sh0[row*256 + (q^(row&7))*8] = v; }
    const int eb = tid>>5, jp = tid&31;
    float cA = c_in[(size_t)(b0+eb)*256 + s*64 + 2*jp];
    float cB = c_in[(size_t)(b0+eb)*256 + s*64 + 2*jp + 1];
    float gxr[2][4];
    #pragma unroll
    for (int nt=0;nt<2;nt++)
      #pragma unroll
      for (int r=0;r<4;r++)
        gxr[nt][r] = gx0[(size_t)(b0 + kg*4 + r)*1024 + gate*256 + s*64 + jblk + nt*16 + c16];
    const int r0 = gate*64 + jblk + c16, r1 = r0 + 16;
    __syncthreads();

    for (int t=0; t<TSTEPS; ++t){
      const int slot = t & (H0_SLOTS-1);
      // throttle vs l1 consumption (every 8 steps, 8-step slack)
      if (((t&7)==0) && t>=16 && tid<64){
        const unsigned need = (unsigned)(t-8);
        for (int it=0; it<SPIN_CAP; ++it){
          unsigned v = need;
          if (tid < 8) v = ld32a(&flagC[grp*8 + tid]);
          if (__all(v >= need)) break;
        }
      }
      f32x4 acc0 = { gxr[0][0], gxr[0][1], gxr[0][2], gxr[0][3] };
      f32x4 acc1 = { gxr[1][0], gxr[1][1], gxr[1][2], gxr[1][3] };
      #pragma unroll
      for (int kt=0;kt<8;kt++){
        half8 af  = *(const half8*)&sh0[c16*256 + ((kt*4+kg)^(c16&7))*8];
        half8 b0f = *(const half8*)&Ws[r0*256 + ((kt*4+kg)^(r0&7))*8];
        half8 b1f = *(const half8*)&Ws[r1*256 + ((kt*4+kg)^(r1&7))*8];
        acc0 = __builtin_amdgcn_mfma_f32_16x16x32_f16(af, b0f, acc0, 0,0,0);
        acc1 = __builtin_amdgcn_mfma_f32_16x16x32_f16(af, b1f, acc1, 0,0,0);
      }
      #pragma unroll
      for (int r=0;r<4;r++){
        gbuf[gate][kg*4+r][jblk + c16]      = acc0[r];
        gbuf[gate][kg*4+r][jblk + 16 + c16] = acc1[r];
      }
      __syncthreads();                      // B1: gbuf ready, sh0 reads done
      { // cell: own 2 cols -> ring (dword sc1)
        int j0 = 2*jp, j1 = 2*jp+1;
        float i0 = sigf (gbuf[0][eb][j0]), i1 = sigf (gbuf[0][eb][j1]);
        float f0 = sigf (gbuf[1][eb][j0]), f1 = sigf (gbuf[1][eb][j1]);
        float g0 = tanh_(gbuf[2][eb][j0]), g1 = tanh_(gbuf[2][eb][j1]);
        float o0 = sigf (gbuf[3][eb][j0]), o1 = sigf (gbuf[3][eb][j1]);
        cA = f0*cA + i0*g0;
        cB = f1*cB + i1*g1;
        unsigned pk = pack2(o0*tanh_(cA), o1*tanh_(cB));
        st32_sc1(&h0r[(((size_t)slot*16+grp)*16 + eb)*256 + s*64 + 2*jp], pk);
      }
      asm volatile("s_waitcnt vmcnt(0)" ::: "memory");
      __syncthreads();                      // B2: all waves' data at MALL
      if (tid == 0) st32a(&h0flag[(grp*16+slot)*4 + s], (unsigned)(t+2));
      if (t+1 < TSTEPS){
        if (tid < 64){                      // spin 3 peer flags (bounded)
          const unsigned want = (unsigned)(t+2);
          for (int it=0; it<SPIN_CAP; ++it){
            unsigned v = want;
            if (tid < 4 && tid != s) v = ld32a(&h0flag[(grp*16+slot)*4 + tid]);
            if (__all(v == want)) break;
          }
        }
        __syncthreads();                    // B3: flags confirmed
        { // coalesced full-tile read (16B/thread) -> stage sh0 = h0(t)
          int row = tid>>5, q = tid&31;
          half8 v = ld128_sc1(&h0r[(((size_t)slot*16+grp)*16 + row)*256 + q*8]);
          *(half8*)&sh0[row*256 + (q^(row&7))*8] = v;
        }
        __syncthreads();                    // B4: sh0 staged
      }
    }
  } else {
    // ---------------- layer 1 ----------------
    const int bb = blk-64, grp = bb>>3, js = bb&7;
    const int b0 = grp*16, jb = js*32;
    const int gate = wv>>1, jhalf = (wv&1)*16;
    _Float16* sh1 = (_Float16*)(Lb + 139264);                  // 8 KB
    float (*gbuf)[16][34] = (float (*)[16][34])(Lb + 147456);  // 8.7 KB

    for (int idx=tid; idx<8192; idx+=512){
      int row = idx>>6, gr = idx&63;
      int g = row>>5, jl = row&31;
      size_t nrow = (size_t)(g*256 + jb + jl);
      const _Float16* src = (gr < 32) ? (Wi1g + nrow*256 + gr*8)
                                      : (Wh1g + nrow*256 + (size_t)(gr-32)*8);
      *(half8*)&Ws[row*512 + (gr^(row&7))*8] = *(const half8*)src;
    }
    { int row = tid>>5, q = tid&31;
      const float* sp = h_in + 65536 + (size_t)(b0+row)*256 + q*8;
      half8 v;
      #pragma unroll
      for (int qq=0;qq<8;qq++) v[qq] = (_Float16)sp[qq];
      *(half8*)&sh1[row*256 + (q^(row&7))*8] = v; }
    const int eb = tid>>4, jp = tid&15;     // cell mapping (tid<256)
    float cA = 0.f, cB = 0.f;
    if (tid < 256){
      cA = c_in[65536 + (size_t)(b0+eb)*256 + jb + 2*jp];
      cB = c_in[65536 + (size_t)(b0+eb)*256 + jb + 2*jp + 1];
    }
    const float bv = bias1[gate*256 + jb + jhalf + c16];
    const int nl = gate*32 + jhalf + c16;
    __syncthreads();

    for (int t=0; t<TSTEPS; ++t){
      const int slot  = t & (H0_SLOTS-1);
      // ---- acquire h0(t): spin 4 flags, coalesced tile read ----
      if (tid < 64){
        const unsigned want = (unsigned)(t+2);
        for (int it=0; it<SPIN_CAP; ++it){
          unsigned v = want;
          if (tid < 4) v = ld32a(&h0flag[(grp*16+slot)*4 + tid]);
          if (__all(v == want)) break;
        }
      }
      __syncthreads();                      // B1: h0 flags confirmed
      { int row = tid>>5, q = tid&31;
        half8 v = ld128_sc1(&h0r[(((size_t)slot*16+grp)*16 + row)*256 + q*8]);
        *(half8*)&sh0[row*256 + (q^(row&7))*8] = v;
      }
      __syncthreads();                      // B2: sh0 = h0(t)
      if (((t&7)==0) && tid==0) st32a(&flagC[grp*8+js], (unsigned)t);
      // ---- partA: bias + Wi1 . h0(t)  (overlaps peers' h1(t-1) lag) ----
      f32x4 acc = { bv, bv, bv, bv };
      #pragma unroll
      for (int kt=0;kt<8;kt++){
        half8 af = *(const half8*)&sh0[c16*256 + ((kt*4+kg)^(c16&7))*8];
        half8 bf = *(const half8*)&Ws[nl*512 + ((kt*4+kg)^(nl&7))*8];
        acc = __builtin_amdgcn_mfma_f32_16x16x32_f16(af, bf, acc, 0,0,0);
      }
      // ---- acquire h1(t-1): spin 8 flags, coalesced tile read ----
      if (t > 0){
        const int ps = (t-1) & (H1_SLOTS-1);
        if (tid < 64){
          const unsigned want = (unsigned)(t+1);
          for (int it=0; it<SPIN_CAP; ++it){
            unsigned v = want;
            if (tid < 8 && tid != js) v = ld32a(&h1flag[(grp*4+ps)*8 + tid]);
            if (__all(v == want)) break;
          }
        }
        __syncthreads();                    // B3: h1 flags confirmed
        { int row = tid>>5, q = tid&31;
          half8 v = ld128_sc1(&h1r[(((size_t)ps*16+grp)*16 + row)*256 + q*8]);
          *(half8*)&sh1[row*256 + (q^(row&7))*8] = v;
        }
      }
      __syncthreads();                      // B4: sh1 = h1(t-1)
      // ---- partB: += Wh1 . h1(t-1) ----
      #pragma unroll
      for (int kt=0;kt<8;kt++){
        half8 af = *(const half8*)&sh1[c16*256 + ((kt*4+kg)^(c16&7))*8];
        half8 bf = *(const half8*)&Ws[nl*512 + ((32+kt*4+kg)^(nl&7))*8];
        acc = __builtin_amdgcn_mfma_f32_16x16x32_f16(af, bf, acc, 0,0,0);
      }
      #pragma unroll
      for (int r=0;r<4;r++) gbuf[gate][kg*4+r][jhalf + c16] = acc[r];
      __syncthreads();                      // B5: gbuf ready, sh1 reads done
      if (tid < 256){       // cell + ring store (dword sc1) + seq1 (plain)
        int j0 = 2*jp, j1 = 2*jp+1;
        float i0 = sigf (gbuf[0][eb][j0]), i1 = sigf (gbuf[0][eb][j1]);
        float f0 = sigf (gbuf[1][eb][j0]), f1 = sigf (gbuf[1][eb][j1]);
        float g0 = tanh_(gbuf[2][eb][j0]), g1 = tanh_(gbuf[2][eb][j1]);
        float o0 = sigf (gbuf[3][eb][j0]), o1 = sigf (gbuf[3][eb][j1]);
        cA = f0*cA + i0*g0;
        cB = f1*cB + i1*g1;
        unsigned pk = pack2(o0*tanh_(cA), o1*tanh_(cB));
        st32_sc1(&h1r[(((size_t)(t&(H1_SLOTS-1))*16+grp)*16 + eb)*256 + jb + 2*jp], pk);
        seq1dw[((size_t)(b0+eb)*TSTEPS + t)*256 + js*16 + jp] = pk;
      }
      asm volatile("s_waitcnt vmcnt(0)" ::: "memory");
      __syncthreads();                      // B6: data at MALL
      if (tid == 0)
        st32a(&h1flag[(grp*4+(t&(H1_SLOTS-1)))*8 + js], (unsigned)(t+2));
    }
  }
}

// ---------------- FC + log_softmax / softmax ----------------
__global__ __launch_bounds__(256) void fc_kernel(
    const _Float16* __restrict__ seq, int pitch,
    const _Float16* __restrict__ fcwh, const float* __restrict__ fcb,
    float* __restrict__ out0, float* __restrict__ out1)
{
  const int tid = threadIdx.x;
  const int w = tid >> 6, l = tid & 63;
  const int col = l & 15, kg = l >> 4;
  const size_t m0 = (size_t)blockIdx.x*64 + (size_t)w*16;
  half8 a[8];
  #pragma unroll
  for (int kt=0;kt<8;kt++)
    a[kt] = *(const half8*)&seq[(m0+col)*(size_t)pitch + kt*32 + kg*8];
  f32x4 acc[16];
  #pragma unroll
  for (int nt=0;nt<16;nt++){
    int n = nt*16 + col;
    float bvl = fcb[n];
    f32x4 c = {bvl,bvl,bvl,bvl};
    const _Float16* wr = fcwh + (size_t)n*256;
    #pragma unroll
    for (int kt=0;kt<8;kt++){
      half8 bf = *(const half8*)&wr[kt*32 + kg*8];
      c = __builtin_amdgcn_mfma_f32_16x16x32_f16(a[kt], bf, c, 0,0,0);
    }
    acc[nt] = c;
  }
  #pragma unroll
  for (int r=0;r<4;r++){
    float mx = -3.0e38f;
    #pragma unroll
    for (int nt=0;nt<16;nt++) mx = fmaxf(mx, acc[nt][r]);
    #pragma unroll
    for (int off=1; off<16; off<<=1) mx = fmaxf(mx, __shfl_xor(mx, off, 64));
    float s = 0.0f;
    #pragma unroll
    for (int nt=0;nt<16;nt++) s += __expf(acc[nt][r]-mx);
    #pragma unroll
    for (int off=1; off<16; off<<=1) s += __shfl_xor(s, off, 64);
    float inv = 1.0f/s;
    float ls  = __logf(s);
    size_t row = m0 + (size_t)kg*4 + r;
    #pragma unroll
    for (int nt=0;nt<16;nt++){
      int n = nt*16 + col;
      float v = acc[nt][r]-mx;
      out0[row*256 + n] = v - ls;
      out1[row*256 + n] = __expf(v)*inv;
    }
  }
}

extern "C" void kernel_launch(void* const* d_in, const int* in_sizes, int n_in,
                              void* d_out, int out_size, void* d_ws, size_t ws_size,
                              hipStream_t stream)
{
  const float* x   = (const float*)d_in[0];
  const float* h0  = (const float*)d_in[1];
  const float* c0  = (const float*)d_in[2];
  const float* Wih = (const float*)d_in[3];
  const float* Whh = (const float*)d_in[4];
  const float* bih = (const float*)d_in[5];
  const float* bhh = (const float*)d_in[6];
  const float* fcw = (const float*)d_in[7];
  const float* fcb = (const float*)d_in[8];
  (void)in_sizes; (void)n_in; (void)out_size; (void)ws_size;

  char* ws = (char*)d_ws;
  _Float16* wh0   = (_Float16*)(ws + 0);            // 512 KB
  _Float16* wi1   = (_Float16*)(ws + (512<<10));    // 512 KB
  _Float16* wh1   = (_Float16*)(ws + (1024<<10));   // 512 KB
  _Float16* fcwh  = (_Float16*)(ws + (1536<<10));   // 128 KB
  float*    bias1 = (float*)   (ws + (1664<<10));   // 4 KB
  float*    gx0   = (float*)   (ws + (1668<<10));   // 1 MB

  // d_out scratch (out0 region, fully overwritten by fc at the end):
  //   h0 ring 2 MB | h1 ring 512 KB | h0flag 4 KB | h1flag 2 KB | flagC 512 B
  char* ob = (char*)d_out;
  float* out0 = (float*)d_out;
  float* out1 = out0 + (size_t)BATCH*TSTEPS*OUTC;
  _Float16* h0r    = (_Float16*)ob;
  _Float16* h1r    = (_Float16*)(ob + (2<<20));
  unsigned* h0flag = (unsigned*)(ob + (3<<20));     // 1024 words
  unsigned* h1flag = h0flag + 1024;                 // 512 words
  unsigned* flagC  = h0flag + 1536;                 // 128 words
  unsigned* seq1dw = (unsigned*)out1;               // seq1 overlay, pitch 512 f16
  _Float16* seq1   = (_Float16*)out1;

  hipLaunchKernelGGL(zero_flags, dim3(7), dim3(256), 0, stream, h0flag, 1664);
  hipLaunchKernelGGL(prep_convert, dim3(1024), dim3(256), 0, stream,
                     Wih, Whh, fcw, bih, bhh, wh0, wi1, wh1, fcwh, bias1);
  hipLaunchKernelGGL(prep_gx0, dim3(1024), dim3(256), 0, stream,
                     x, Wih, bih, bhh, gx0);
  hipLaunchKernelGGL(lstm7, dim3(192), dim3(512), 0, stream,
                     gx0, wh0, wi1, wh1, bias1, h0, c0,
                     seq1dw, h0r, h1r, h0flag, h1flag, flagC);
  hipLaunchKernelGGL(fc_kernel, dim3(2048), dim3(256), 0, stream,
                     seq1, 512, fcwh, fcb, out0, out1);
}